// Round 1
// baseline (381.792 us; speedup 1.0000x reference)
//
#include <hip/hip_runtime.h>

// MeanAggregator: out[b,:] = sum_s (w[b,s] * features[idx[b,s], :]) / sum_s w[b,s]
// B=16384, S=32, D=512, features [100000,512] f32.
// Memory-bound gather; features (205 MB) fits in 256 MB L3 -> most of the
// 1.07 GB gathered volume is cache-tier traffic.

#define EMBED_DIM   512
#define NUM_SAMPLE  32
#define VECS_PER_ROW (EMBED_DIM / 4)   // 128 float4 per feature row

__global__ __launch_bounds__(256) void mean_agg_kernel(
    const float* __restrict__ features,
    const float* __restrict__ neigh_weight,
    const int*   __restrict__ neigh_idx,
    float*       __restrict__ out,
    int batch)
{
    const int half = threadIdx.x >> 7;      // 0/1: which row of the pair this thread serves
    const int lane = threadIdx.x & 127;     // float4 column within the row
    const int row  = blockIdx.x * 2 + half;

    __shared__ float s_w[2][NUM_SAMPLE];
    __shared__ int   s_idx[2][NUM_SAMPLE];

    // Stage this row's 32 weights + indices into LDS (first 32 lanes of each half).
    if (row < batch && lane < NUM_SAMPLE) {
        s_w[half][lane]   = neigh_weight[row * NUM_SAMPLE + lane];
        s_idx[half][lane] = neigh_idx[row * NUM_SAMPLE + lane];
    }
    __syncthreads();
    if (row >= batch) return;

    // Row sum of weights (broadcast LDS reads: same address across lanes = free).
    float sum = 0.0f;
    #pragma unroll
    for (int s = 0; s < NUM_SAMPLE; ++s) sum += s_w[half][s];
    const float inv = 1.0f / sum;

    const float4* __restrict__ f4 = reinterpret_cast<const float4*>(features);
    float4 acc = make_float4(0.0f, 0.0f, 0.0f, 0.0f);

    // Gather-accumulate. unroll 8 -> 8 independent global loads in flight/thread.
    #pragma unroll 8
    for (int s = 0; s < NUM_SAMPLE; ++s) {
        const float  w   = s_w[half][s];
        const size_t off = (size_t)s_idx[half][s] * VECS_PER_ROW + lane;
        const float4 v   = f4[off];
        acc.x = fmaf(w, v.x, acc.x);
        acc.y = fmaf(w, v.y, acc.y);
        acc.z = fmaf(w, v.z, acc.z);
        acc.w = fmaf(w, v.w, acc.w);
    }

    acc.x *= inv; acc.y *= inv; acc.z *= inv; acc.w *= inv;
    reinterpret_cast<float4*>(out)[(size_t)row * VECS_PER_ROW + lane] = acc;
}

extern "C" void kernel_launch(void* const* d_in, const int* in_sizes, int n_in,
                              void* d_out, int out_size, void* d_ws, size_t ws_size,
                              hipStream_t stream) {
    const float* features     = (const float*)d_in[0];
    const float* neigh_weight = (const float*)d_in[1];
    const int*   neigh_idx    = (const int*)d_in[2];
    float*       out          = (float*)d_out;

    const int batch = in_sizes[1] / NUM_SAMPLE;          // 16384
    const int grid  = (batch + 1) / 2;                   // 2 rows per 256-thread block

    mean_agg_kernel<<<dim3(grid), dim3(256), 0, stream>>>(
        features, neigh_weight, neigh_idx, out, batch);
}